// Round 11
// baseline (1480.094 us; speedup 1.0000x reference)
//
#include <hip/hip_runtime.h>
#include <hip/hip_bf16.h>
#include <stdint.h>

#define B_ 8192
#define IN_ 1024
#define H_ 1024
#define OUT_ 512
#define KC 2048   // IN_+H_
#define N4 4096   // 4*H_

typedef __bf16 bf16_t;
typedef __bf16 bf16x8 __attribute__((ext_vector_type(8)));
typedef float f32x4 __attribute__((ext_vector_type(4)));

__device__ __forceinline__ void gload_lds16(const void* g, void* l) {
  __builtin_amdgcn_global_load_lds(
      (const __attribute__((address_space(1))) uint32_t*)g,
      (__attribute__((address_space(3))) uint32_t*)l, 16, 0, 0);
}

__device__ __forceinline__ float fsigmoid(float x) {
  return __builtin_amdgcn_rcpf(1.0f + __expf(-x));
}
__device__ __forceinline__ float ftanh(float x) {
  return 2.0f * __builtin_amdgcn_rcpf(1.0f + __expf(-2.0f * x)) - 1.0f;
}

// ---------------- merged prep kernel (R9, unchanged) ----------------
__global__ __launch_bounds__(256) void prep_all(
    const float* __restrict__ x, const float* __restrict__ h,
    const float* __restrict__ Wi, const float* __restrict__ Wf,
    const float* __restrict__ Wo, const float* __restrict__ Wc,
    const float* __restrict__ Wy, bf16_t* __restrict__ combined,
    bf16_t* __restrict__ dstG, bf16_t* __restrict__ dstY) {
  __shared__ float tile[64][65];
  const int bxid = blockIdx.x;
  const int t = threadIdx.x;

  if (bxid < 8192) {
    const int row = bxid;
    const int j = t * 8;
    const float* src = (j < IN_) ? (x + (size_t)row * IN_ + j)
                                 : (h + (size_t)row * H_ + (j - IN_));
    float4 a = ((const float4*)src)[0];
    float4 b = ((const float4*)src)[1];
    bf16x8 v;
    v[0] = (bf16_t)a.x; v[1] = (bf16_t)a.y; v[2] = (bf16_t)a.z; v[3] = (bf16_t)a.w;
    v[4] = (bf16_t)b.x; v[5] = (bf16_t)b.y; v[6] = (bf16_t)b.z; v[7] = (bf16_t)b.w;
    *(bf16x8*)(combined + (size_t)row * KC + j) = v;
    return;
  }

  const float* src;
  bf16_t* dst;
  int K, N, RS, RO, gx, gy;
  const int idx = bxid - 8192;
  if (idx < 2048) {
    const int z = idx >> 9;
    const int rem = idx & 511;
    gx = rem & 15; gy = rem >> 4;
    src = (z == 0) ? Wi : (z == 1) ? Wf : (z == 2) ? Wo : Wc;
    dst = dstG; K = KC; N = H_; RS = 4; RO = z;
  } else {
    const int i2 = idx - 2048;
    gx = i2 & 7; gy = i2 >> 3;
    src = Wy; dst = dstY; K = H_; N = OUT_; RS = 1; RO = 0;
  }
  const int k0 = gy * 64, n0 = gx * 64;
  const int tr = t >> 4, tc4 = (t & 15) * 4;
#pragma unroll
  for (int r = 0; r < 4; ++r) {
    const int k = tr + r * 16;
    float4 v = *(const float4*)(src + (size_t)(k0 + k) * N + n0 + tc4);
    tile[k][tc4] = v.x; tile[k][tc4 + 1] = v.y;
    tile[k][tc4 + 2] = v.z; tile[k][tc4 + 3] = v.w;
  }
  __syncthreads();
  const int nr = t >> 3, kc8 = (t & 7) * 8;
#pragma unroll
  for (int r = 0; r < 2; ++r) {
    const int n = nr + r * 32;
    bf16x8 v;
#pragma unroll
    for (int q = 0; q < 8; ++q) v[q] = (bf16_t)tile[kc8 + q][n];
    *(bf16x8*)(dst + (size_t)((n0 + n) * RS + RO) * K + k0 + kc8) = v;
  }
}

// ---------------- GEMM1: 256x256, BK=32, 2 LDS bufs (64 KB), 2 blocks/CU ---
// Cross-BLOCK overlap covers the per-tile vmcnt(0)+barrier drain: while this
// block drains, the co-resident block is mid-MFMA (m114 mechanism).
// Body t: 12 ds_read frags(t, buf t&1) | STAGE(t+1 -> other buf) |
//         32 indep MFMA | vmcnt(0) | barrier.
__global__ __launch_bounds__(512, 4) void gemm1_occ(
    const bf16_t* __restrict__ A, const bf16_t* __restrict__ Bt,
    const float* __restrict__ c_in,
    const float* __restrict__ bi, const float* __restrict__ bfg,
    const float* __restrict__ bo, const float* __restrict__ bc,
    float* __restrict__ h_out, float* __restrict__ c_out,
    bf16_t* __restrict__ hb) {
  constexpr int K = KC;
  constexpr int NT = K / 32;  // 64 K-tiles of BK=32
  __shared__ char lds[65536];  // 2 bufs x (A 16KB | B 16KB)

  const int tid = threadIdx.x;
  const int lane = tid & 63;
  const int w = tid >> 6;
  const int wr = w >> 2, wc = w & 3;
  const int l15 = lane & 15, l4 = lane >> 4;

  // XCD-bijective swizzle: 512 blocks, 8 XCDs, 64 blocks/XCD.
  const int wg = blockIdx.x;
  const int swz = (wg & 7) * 64 + (wg >> 3);
  const int bx = swz >> 5;
  const int by = swz & 31;
  const int m0 = by * 256, n0 = bx * 256;

  // ---- staging: wave w owns A rows [w*32, w*32+32) and B rows same ----
  const int jrow = lane >> 2;
  const int jcswz = ((lane & 3) * 16) ^ ((lane >> 5) << 5);
  const char* AsrcS =
      (const char*)A + (size_t)(m0 + w * 32 + jrow) * (K * 2) + jcswz;
  const char* BsrcS =
      (const char*)Bt + (size_t)(n0 + w * 32 + jrow) * (K * 2) + jcswz;
  const int aw0 = w * 2048;
  const int bw0 = 16384 + w * 2048;

#define STAGE(tt) do {                                                     \
    char* d_ = lds + ((tt) & 1) * 32768;                                   \
    const size_t kb_ = (size_t)(tt) * 64;                                  \
    gload_lds16(AsrcS + kb_, d_ + aw0);                                    \
    gload_lds16(AsrcS + (size_t)16 * (K * 2) + kb_, d_ + aw0 + 1024);      \
    gload_lds16(BsrcS + kb_, d_ + bw0);                                    \
    gload_lds16(BsrcS + (size_t)16 * (K * 2) + kb_, d_ + bw0 + 1024);      \
  } while (0)

  // ---- read offsets (counter-verified 0-conflict pattern) ----
  const int rdoff = l15 * 64 + ((l4 * 16) ^ ((l15 >> 3) << 5));
  const int aro = wr * 8192 + rdoff;           // + mi*1024
  const int bro = 16384 + wc * 4096 + rdoff;   // + ni*1024

  f32x4 acc[8][4] = {};

  // ---- prologue: tile 0 into buf 0 ----
  STAGE(0);
  asm volatile("s_waitcnt vmcnt(0)" ::: "memory");
  __builtin_amdgcn_s_barrier();

#pragma unroll 2
  for (int t = 0; t < NT; ++t) {
    const char* bufp = lds + (t & 1) * 32768;

    // 12 ds_read_b128: fragment set for tile t (single k-step, K=32)
    bf16x8 fa[8], fbq[4];
#pragma unroll
    for (int mi = 0; mi < 8; ++mi)
      fa[mi] = *(const bf16x8*)(bufp + aro + mi * 1024);
#pragma unroll
    for (int ni = 0; ni < 4; ++ni)
      fbq[ni] = *(const bf16x8*)(bufp + bro + ni * 1024);

    // stage next tile into the other buffer (lands under the MFMAs)
    if (t + 1 < NT) STAGE(t + 1);

    // 32 mutually-independent MFMAs
    __builtin_amdgcn_s_setprio(1);
#pragma unroll
    for (int mi = 0; mi < 8; ++mi)
#pragma unroll
      for (int ni = 0; ni < 4; ++ni)
        acc[mi][ni] = __builtin_amdgcn_mfma_f32_16x16x32_bf16(
            fa[mi], fbq[ni], acc[mi][ni], 0, 0, 0);
    __builtin_amdgcn_s_setprio(0);

    if (t + 1 < NT) asm volatile("s_waitcnt vmcnt(0)" ::: "memory");
    __builtin_amdgcn_s_barrier();  // drain covered by co-resident block
  }

  // ---- fused LSTM epilogue: 4 sub-passes in the single 64 KB buffer ----
  const int hc0 = n0 >> 2;
  const int ehc = tid & 63;
  const int err0 = (tid >> 6) * 8;
  const float bI = bi[hc0 + ehc];
  const float bF = bfg[hc0 + ehc];
  const float bO = bo[hc0 + ehc];
  const float bC = bc[hc0 + ehc];

  float cpre[2][2][8];
#pragma unroll
  for (int p = 0; p < 2; ++p)
#pragma unroll
    for (int half = 0; half < 2; ++half)
#pragma unroll
      for (int r = 0; r < 8; ++r)
        cpre[p][half][r] =
            c_in[(size_t)(m0 + half * 128 + p * 64 + err0 + r) * H_ + hc0 + ehc];

  for (int p = 0; p < 2; ++p) {
#pragma unroll
    for (int half = 0; half < 2; ++half) {
      __builtin_amdgcn_s_barrier();  // previous sub-pass reads done
      if (wr == half) {
        float* dst = (float*)lds;
        const int mib = p * 4;
#pragma unroll
        for (int mi = 0; mi < 4; ++mi)
#pragma unroll
          for (int ni = 0; ni < 4; ++ni) {
            const int col = wc * 64 + ni * 16 + l15;
            const int hc = col >> 2, g = col & 3;
#pragma unroll
            for (int q = 0; q < 4; ++q) {
              const int rr = mi * 16 + l4 * 4 + q;
              dst[rr * 256 + ((hc ^ rr) * 4) + g] = acc[mib + mi][ni][q];
            }
          }
      }
      __builtin_amdgcn_s_barrier();
      const float* src = (const float*)lds;
#pragma unroll
      for (int r = 0; r < 8; ++r) {
        const int rr = err0 + r;
        f32x4 gq = *(const f32x4*)&src[rr * 256 + ((ehc ^ rr) * 4)];
        const size_t gidx =
            (size_t)(m0 + half * 128 + p * 64 + rr) * H_ + hc0 + ehc;
        float I = fsigmoid(gq[0] + bI);
        float F = fsigmoid(gq[1] + bF);
        float O = fsigmoid(gq[2] + bO);
        float Ct = ftanh(gq[3] + bC);
        float cn = F * cpre[p][half][r] + I * Ct;
        float hn = O * ftanh(cn);
        c_out[gidx] = cn;
        h_out[gidx] = hn;
        hb[gidx] = (bf16_t)hn;
      }
    }
  }
#undef STAGE
}

// ---------------- GEMM2 (R9, unchanged) ----------------
__global__ __launch_bounds__(256) void gemm_bt_f32(
    const bf16_t* __restrict__ A, const bf16_t* __restrict__ Bt,
    float* __restrict__ Cout, const float* __restrict__ bias,
    int M, int N, int K) {
  __shared__ bf16_t As[128 * 64];
  __shared__ bf16_t Bs[128 * 64];
  const int tid = threadIdx.x;
  const int lane = tid & 63;
  const int wave = tid >> 6;
  const int m0 = blockIdx.y * 128;
  const int n0 = blockIdx.x * 128;
  const int wr = wave >> 1, wc = wave & 1;
  const int l15 = lane & 15, l4 = lane >> 4;

  f32x4 acc[4][4] = {};

  const int srow = tid >> 3;
  const int slot = tid & 7;
  const int skelb = (slot * 16) ^ ((srow & 7) << 4);
  const char* aSrc = (const char*)A + (size_t)(m0 + srow) * (K * 2) + skelb;
  const char* bSrc = (const char*)Bt + (size_t)(n0 + srow) * (K * 2) + skelb;
  char* aL = (char*)As + wave * 1024;
  char* bL = (char*)Bs + wave * 1024;

  const int xr = (l15 & 7) << 4;

  for (int kt = 0; kt < K; kt += 64) {
    __syncthreads();
#pragma unroll
    for (int i = 0; i < 4; ++i) {
      gload_lds16(aSrc + ((size_t)i * 32 * K + kt) * 2, aL + i * 4096);
      gload_lds16(bSrc + ((size_t)i * 32 * K + kt) * 2, bL + i * 4096);
    }
    __syncthreads();
#pragma unroll
    for (int kk = 0; kk < 2; ++kk) {
      bf16x8 af[4], bq[4];
#pragma unroll
      for (int mi = 0; mi < 4; ++mi)
        af[mi] = *(const bf16x8*)((const char*)As +
                 (wr * 64 + mi * 16 + l15) * 128 + ((kk * 64 + l4 * 16) ^ xr));
#pragma unroll
      for (int ni = 0; ni < 4; ++ni)
        bq[ni] = *(const bf16x8*)((const char*)Bs +
                 (wc * 64 + ni * 16 + l15) * 128 + ((kk * 64 + l4 * 16) ^ xr));
#pragma unroll
      for (int mi = 0; mi < 4; ++mi)
#pragma unroll
        for (int ni = 0; ni < 4; ++ni)
          acc[mi][ni] = __builtin_amdgcn_mfma_f32_16x16x32_bf16(
              af[mi], bq[ni], acc[mi][ni], 0, 0, 0);
    }
  }

  const int col = n0 + wc * 64 + l15;
  const int row0 = m0 + wr * 64 + l4 * 4;
#pragma unroll
  for (int ni = 0; ni < 4; ++ni) {
    const float bv = bias[col + ni * 16];
#pragma unroll
    for (int mi = 0; mi < 4; ++mi)
#pragma unroll
      for (int q = 0; q < 4; ++q)
        Cout[(size_t)(row0 + mi * 16 + q) * N + col + ni * 16] =
            acc[mi][ni][q] + bv;
  }
}

// ---------------- launcher ----------------
extern "C" void kernel_launch(void* const* d_in, const int* in_sizes, int n_in,
                              void* d_out, int out_size, void* d_ws,
                              size_t ws_size, hipStream_t stream) {
  const float* x = (const float*)d_in[0];
  const float* h = (const float*)d_in[1];
  const float* c = (const float*)d_in[2];
  const float* Wi = (const float*)d_in[3];
  const float* bi = (const float*)d_in[4];
  const float* Wf = (const float*)d_in[5];
  const float* bfg = (const float*)d_in[6];
  const float* Wo = (const float*)d_in[7];
  const float* bo = (const float*)d_in[8];
  const float* Wc = (const float*)d_in[9];
  const float* bc = (const float*)d_in[10];
  const float* Wy = (const float*)d_in[11];
  const float* by = (const float*)d_in[12];

  char* ws = (char*)d_ws;
  bf16_t* combined = (bf16_t*)ws;                       // 33.5 MB
  bf16_t* Wt = (bf16_t*)(ws + 33554432);                // 16.8 MB (interleaved)
  bf16_t* Wyt = (bf16_t*)(ws + 33554432 + 16777216);    // 1 MB
  bf16_t* hb = (bf16_t*)(ws + 33554432 + 16777216 + 1048576);  // 16.8 MB

  float* y_out = (float*)d_out;
  float* h_out = y_out + (size_t)B_ * OUT_;
  float* c_out = h_out + (size_t)B_ * H_;

  prep_all<<<dim3(8192 + 2048 + 128), dim3(256), 0, stream>>>(
      x, h, Wi, Wf, Wo, Wc, Wy, combined, Wt, Wyt);

  gemm1_occ<<<dim3((B_ / 256) * (N4 / 256)), dim3(512), 0, stream>>>(
      combined, Wt, c, bi, bfg, bo, bc, h_out, c_out, hb);

  gemm_bt_f32<<<dim3(OUT_ / 128, B_ / 128), dim3(256), 0, stream>>>(
      hb, Wyt, y_out, by, B_, OUT_, H_);
}

// Round 12
// 185.354 us; speedup vs baseline: 7.9852x; 7.9852x over previous
//
#include <hip/hip_runtime.h>
#include <hip/hip_bf16.h>
#include <stdint.h>

#define B_ 8192
#define IN_ 1024
#define H_ 1024
#define OUT_ 512
#define KC 2048   // IN_+H_
#define N4 4096   // 4*H_

typedef __bf16 bf16_t;
typedef __bf16 bf16x8 __attribute__((ext_vector_type(8)));
typedef float f32x4 __attribute__((ext_vector_type(4)));

__device__ __forceinline__ void gload_lds16(const void* g, void* l) {
  __builtin_amdgcn_global_load_lds(
      (const __attribute__((address_space(1))) uint32_t*)g,
      (__attribute__((address_space(3))) uint32_t*)l, 16, 0, 0);
}

__device__ __forceinline__ float fsigmoid(float x) {
  return __builtin_amdgcn_rcpf(1.0f + __expf(-x));
}
__device__ __forceinline__ float ftanh(float x) {
  return 2.0f * __builtin_amdgcn_rcpf(1.0f + __expf(-2.0f * x)) - 1.0f;
}

// ---------------- pack kernels ----------------

__global__ __launch_bounds__(256) void pack_combined(
    const float* __restrict__ x, const float* __restrict__ h,
    bf16_t* __restrict__ out) {
  const int row = blockIdx.x;
  const int j = threadIdx.x * 8;
  const float* src = (j < IN_) ? (x + (size_t)row * IN_ + j)
                               : (h + (size_t)row * H_ + (j - IN_));
  float4 a = ((const float4*)src)[0];
  float4 b = ((const float4*)src)[1];
  bf16x8 v;
  v[0] = (bf16_t)a.x; v[1] = (bf16_t)a.y; v[2] = (bf16_t)a.z; v[3] = (bf16_t)a.w;
  v[4] = (bf16_t)b.x; v[5] = (bf16_t)b.y; v[6] = (bf16_t)b.z; v[7] = (bf16_t)b.w;
  *(bf16x8*)(out + (size_t)row * KC + j) = v;
}

// One launch for all weight transposes.
// z<4: gate weight g -> dst row n*4+g, K=KC, N=H_. z==4: Wy (bx<8, by<16).
__global__ __launch_bounds__(256) void transpose_all(
    const float* __restrict__ Wi, const float* __restrict__ Wf,
    const float* __restrict__ Wo, const float* __restrict__ Wc,
    const float* __restrict__ Wy, bf16_t* __restrict__ dstG,
    bf16_t* __restrict__ dstY) {
  const int z = blockIdx.z;
  const float* src;
  bf16_t* dst;
  int K, N, RS, RO;
  if (z < 4) {
    src = (z == 0) ? Wi : (z == 1) ? Wf : (z == 2) ? Wo : Wc;
    dst = dstG; K = KC; N = H_; RS = 4; RO = z;
  } else {
    if (blockIdx.x >= 8 || blockIdx.y >= 16) return;
    src = Wy; dst = dstY; K = H_; N = OUT_; RS = 1; RO = 0;
  }
  __shared__ float tile[64][65];
  const int k0 = blockIdx.y * 64, n0 = blockIdx.x * 64;
  const int t = threadIdx.x;
  const int tr = t >> 4, tc4 = (t & 15) * 4;
#pragma unroll
  for (int r = 0; r < 4; ++r) {
    const int k = tr + r * 16;
    float4 v = *(const float4*)(src + (size_t)(k0 + k) * N + n0 + tc4);
    tile[k][tc4] = v.x; tile[k][tc4 + 1] = v.y;
    tile[k][tc4 + 2] = v.z; tile[k][tc4 + 3] = v.w;
  }
  __syncthreads();
  const int nr = t >> 3, kc8 = (t & 7) * 8;
#pragma unroll
  for (int r = 0; r < 2; ++r) {
    const int n = nr + r * 32;
    bf16x8 v;
#pragma unroll
    for (int q = 0; q < 8; ++q) v[q] = (bf16_t)tile[kc8 + q][n];
    *(bf16x8*)(dst + (size_t)((n0 + n) * RS + RO) * K + k0 + kc8) = v;
  }
}

// ---------------- GEMM1: 256x256, 1 barrier/K-tile, fused LSTM epilogue ----
// (R7 structure — best measured: free-run tile, all staging to other buf)
__global__ __launch_bounds__(512) void gemm1_8ph(
    const bf16_t* __restrict__ A, const bf16_t* __restrict__ Bt,
    const float* __restrict__ c_in,
    const float* __restrict__ bi, const float* __restrict__ bfg,
    const float* __restrict__ bo, const float* __restrict__ bc,
    float* __restrict__ h_out, float* __restrict__ c_out,
    bf16_t* __restrict__ hb) {
  constexpr int K = KC;
  constexpr int NT = K / 64;  // 32 K-tiles
  __shared__ char lds[131072];

  const int tid = threadIdx.x;
  const int lane = tid & 63;
  const int w = tid >> 6;
  const int wr = w >> 2, wc = w & 3;
  const int l15 = lane & 15, l4 = lane >> 4;

  // XCD-bijective swizzle: 512 blocks, 8 XCDs, 64 blocks/XCD.
  const int wg = blockIdx.x;
  const int swz = (wg & 7) * 64 + (wg >> 3);
  const int bx = swz >> 5;   // 0..15
  const int by = swz & 31;   // 0..31
  const int m0 = by * 256, n0 = bx * 256;

  // ---- staging: per-lane pre-swizzled global source ----
  const int jrow = lane >> 2;
  const int jcol = ((lane & 3) * 16) ^ ((lane >> 5) << 5);
  const char* Asrc = (const char*)A + (size_t)(m0 + w * 16 + jrow) * (K * 2) + jcol;
  const char* Bsrc = (const char*)Bt + (size_t)(n0 + w * 16 + jrow) * (K * 2) + jcol;
  char* ldsA = lds;
  char* ldsB = lds + 32768;
  const int wchunk = w * 2048;

#define STG_A(buf, h, tt) do {                                            \
    gload_lds16(Asrc + (size_t)(h) * 128 * (K * 2) + (size_t)(tt) * 128,  \
                ldsA + (buf) * 65536 + (h) * 16384 + wchunk);             \
    gload_lds16(Asrc + (size_t)(h) * 128 * (K * 2) + (size_t)(tt) * 128 + 64, \
                ldsA + (buf) * 65536 + (h) * 16384 + wchunk + 1024);      \
  } while (0)
#define STG_B(buf, h, tt) do {                                            \
    gload_lds16(Bsrc + (size_t)(h) * 128 * (K * 2) + (size_t)(tt) * 128,  \
                ldsB + (buf) * 65536 + (h) * 16384 + wchunk);             \
    gload_lds16(Bsrc + (size_t)(h) * 128 * (K * 2) + (size_t)(tt) * 128 + 64, \
                ldsB + (buf) * 65536 + (h) * 16384 + wchunk + 1024);      \
  } while (0)

  const int rdoff = l15 * 64 + ((l4 * 16) ^ ((l15 >> 3) << 5));
  const char* ldsArd = lds + wr * 16384 + rdoff;
  const char* ldsBrd = lds + 32768 + (wc >> 1) * 16384 + (wc & 1) * 8192 + rdoff;

  f32x4 acc[8][4] = {};
  bf16x8 falo[4][2], fahi[4][2], fb[4][2];

  // ---- prologue: tile 0 into buf 0 ----
  STG_B(0, 0, 0); STG_B(0, 1, 0); STG_A(0, 0, 0); STG_A(0, 1, 0);
  asm volatile("s_waitcnt vmcnt(0)" ::: "memory");
  __builtin_amdgcn_s_barrier();

  for (int t = 0; t < NT; ++t) {
    const int buf = t & 1;
    const int nbuf = buf ^ 1;
    const char* ard = ldsArd + buf * 65536;
    const char* brd = ldsBrd + buf * 65536;
    const bool st1 = (t + 1 < NT);

    // batch 1 (8 reads): falo[0..1], fb[0..1]
#pragma unroll
    for (int mi = 0; mi < 2; ++mi)
#pragma unroll
      for (int kk = 0; kk < 2; ++kk)
        falo[mi][kk] = *(const bf16x8*)(ard + mi * 2048 + kk * 1024);
#pragma unroll
    for (int ni = 0; ni < 2; ++ni)
#pragma unroll
      for (int kk = 0; kk < 2; ++kk)
        fb[ni][kk] = *(const bf16x8*)(brd + ni * 2048 + kk * 1024);

    // stage tile t+1 into the other buffer (8 gloads)
    if (st1) {
      STG_B(nbuf, 0, t + 1); STG_B(nbuf, 1, t + 1);
      STG_A(nbuf, 0, t + 1); STG_A(nbuf, 1, t + 1);
    }

    // batch 2 (8 reads): falo[2..3], fb[2..3]
#pragma unroll
    for (int mi = 2; mi < 4; ++mi)
#pragma unroll
      for (int kk = 0; kk < 2; ++kk)
        falo[mi][kk] = *(const bf16x8*)(ard + mi * 2048 + kk * 1024);
#pragma unroll
    for (int ni = 2; ni < 4; ++ni)
#pragma unroll
      for (int kk = 0; kk < 2; ++kk)
        fb[ni][kk] = *(const bf16x8*)(brd + ni * 2048 + kk * 1024);

    // batch 3 (8 reads): fahi[0..3]
#pragma unroll
    for (int mi = 0; mi < 4; ++mi)
#pragma unroll
      for (int kk = 0; kk < 2; ++kk)
        fahi[mi][kk] = *(const bf16x8*)(ard + (mi + 4) * 2048 + kk * 1024);

    // C0 (8): falo01 x fb01
    __builtin_amdgcn_s_setprio(1);
#pragma unroll
    for (int kk = 0; kk < 2; ++kk)
#pragma unroll
      for (int mi = 0; mi < 2; ++mi)
#pragma unroll
        for (int ni = 0; ni < 2; ++ni)
          acc[mi][ni] = __builtin_amdgcn_mfma_f32_16x16x32_bf16(
              falo[mi][kk], fb[ni][kk], acc[mi][ni], 0, 0, 0);

    // C1 (16): falo01 x fb23 + falo23 x fb01
#pragma unroll
    for (int kk = 0; kk < 2; ++kk) {
#pragma unroll
      for (int mi = 0; mi < 2; ++mi)
#pragma unroll
        for (int ni = 2; ni < 4; ++ni)
          acc[mi][ni] = __builtin_amdgcn_mfma_f32_16x16x32_bf16(
              falo[mi][kk], fb[ni][kk], acc[mi][ni], 0, 0, 0);
#pragma unroll
      for (int mi = 2; mi < 4; ++mi)
#pragma unroll
        for (int ni = 0; ni < 2; ++ni)
          acc[mi][ni] = __builtin_amdgcn_mfma_f32_16x16x32_bf16(
              falo[mi][kk], fb[ni][kk], acc[mi][ni], 0, 0, 0);
    }

    // C2 (8): falo23 x fb23
#pragma unroll
    for (int kk = 0; kk < 2; ++kk)
#pragma unroll
      for (int mi = 2; mi < 4; ++mi)
#pragma unroll
        for (int ni = 2; ni < 4; ++ni)
          acc[mi][ni] = __builtin_amdgcn_mfma_f32_16x16x32_bf16(
              falo[mi][kk], fb[ni][kk], acc[mi][ni], 0, 0, 0);

    // C3 (32): fahi x fb (all)
#pragma unroll
    for (int kk = 0; kk < 2; ++kk)
#pragma unroll
      for (int mi = 0; mi < 4; ++mi)
#pragma unroll
        for (int ni = 0; ni < 4; ++ni)
          acc[mi + 4][ni] = __builtin_amdgcn_mfma_f32_16x16x32_bf16(
              fahi[mi][kk], fb[ni][kk], acc[mi + 4][ni], 0, 0, 0);
    __builtin_amdgcn_s_setprio(0);

    if (st1) asm volatile("s_waitcnt vmcnt(0)" ::: "memory");
    __builtin_amdgcn_s_barrier();  // tile t+1 resident; buf roles swap
  }

  // ---- fused LSTM epilogue (2 passes, both LDS halves) ----
  const int hc0 = n0 >> 2;
  const int ehc = tid & 63;
  const int err0 = (tid >> 6) * 8;
  const float bI = bi[hc0 + ehc];
  const float bF = bfg[hc0 + ehc];
  const float bO = bo[hc0 + ehc];
  const float bC = bc[hc0 + ehc];

  // prefetch c_in (hides under LDS dump + transcendentals)
  float cpre[2][2][8];
#pragma unroll
  for (int p = 0; p < 2; ++p)
#pragma unroll
    for (int half = 0; half < 2; ++half)
#pragma unroll
      for (int r = 0; r < 8; ++r)
        cpre[p][half][r] =
            c_in[(size_t)(m0 + half * 128 + p * 64 + err0 + r) * H_ + hc0 + ehc];

  for (int p = 0; p < 2; ++p) {
    __builtin_amdgcn_s_barrier();
    {
      float* dst = (float*)(lds + wr * 65536);
      const int mib = p * 4;
#pragma unroll
      for (int mi = 0; mi < 4; ++mi)
#pragma unroll
        for (int ni = 0; ni < 4; ++ni) {
          const int col = wc * 64 + ni * 16 + l15;
          const int hc = col >> 2, g = col & 3;
#pragma unroll
          for (int q = 0; q < 4; ++q) {
            const int rr = mi * 16 + l4 * 4 + q;
            dst[rr * 256 + ((hc ^ rr) * 4) + g] = acc[mib + mi][ni][q];
          }
        }
    }
    __builtin_amdgcn_s_barrier();
#pragma unroll
    for (int half = 0; half < 2; ++half) {
      const float* src = (const float*)(lds + half * 65536);
#pragma unroll
      for (int r = 0; r < 8; ++r) {
        const int rr = err0 + r;
        f32x4 gq = *(const f32x4*)&src[rr * 256 + ((ehc ^ rr) * 4)];
        const size_t gidx =
            (size_t)(m0 + half * 128 + p * 64 + rr) * H_ + hc0 + ehc;
        float I = fsigmoid(gq[0] + bI);
        float F = fsigmoid(gq[1] + bF);
        float O = fsigmoid(gq[2] + bO);
        float Ct = ftanh(gq[3] + bC);
        float cn = F * cpre[p][half][r] + I * Ct;
        float hn = O * ftanh(cn);
        c_out[gidx] = cn;
        h_out[gidx] = hn;
        hb[gidx] = (bf16_t)hn;
      }
    }
  }
#undef STG_A
#undef STG_B
}

// ---------------- GEMM2 (m97 structure + LDS swizzle, f32 out + bias) ------
__global__ __launch_bounds__(256) void gemm_bt_f32(
    const bf16_t* __restrict__ A, const bf16_t* __restrict__ Bt,
    float* __restrict__ Cout, const float* __restrict__ bias,
    int M, int N, int K) {
  __shared__ bf16_t As[128 * 64];
  __shared__ bf16_t Bs[128 * 64];
  const int tid = threadIdx.x;
  const int lane = tid & 63;
  const int wave = tid >> 6;
  const int m0 = blockIdx.y * 128;
  const int n0 = blockIdx.x * 128;
  const int wr = wave >> 1, wc = wave & 1;
  const int l15 = lane & 15, l4 = lane >> 4;

  f32x4 acc[4][4] = {};

  const int srow = tid >> 3;
  const int slot = tid & 7;
  const int skelb = (slot * 16) ^ ((srow & 7) << 4);
  const char* aSrc = (const char*)A + (size_t)(m0 + srow) * (K * 2) + skelb;
  const char* bSrc = (const char*)Bt + (size_t)(n0 + srow) * (K * 2) + skelb;
  char* aL = (char*)As + wave * 1024;
  char* bL = (char*)Bs + wave * 1024;

  const int xr = (l15 & 7) << 4;

  for (int kt = 0; kt < K; kt += 64) {
    __syncthreads();
#pragma unroll
    for (int i = 0; i < 4; ++i) {
      gload_lds16(aSrc + ((size_t)i * 32 * K + kt) * 2, aL + i * 4096);
      gload_lds16(bSrc + ((size_t)i * 32 * K + kt) * 2, bL + i * 4096);
    }
    __syncthreads();
#pragma unroll
    for (int kk = 0; kk < 2; ++kk) {
      bf16x8 af[4], bq[4];
#pragma unroll
      for (int mi = 0; mi < 4; ++mi)
        af[mi] = *(const bf16x8*)((const char*)As +
                 (wr * 64 + mi * 16 + l15) * 128 + ((kk * 64 + l4 * 16) ^ xr));
#pragma unroll
      for (int ni = 0; ni < 4; ++ni)
        bq[ni] = *(const bf16x8*)((const char*)Bs +
                 (wc * 64 + ni * 16 + l15) * 128 + ((kk * 64 + l4 * 16) ^ xr));
#pragma unroll
      for (int mi = 0; mi < 4; ++mi)
#pragma unroll
        for (int ni = 0; ni < 4; ++ni)
          acc[mi][ni] = __builtin_amdgcn_mfma_f32_16x16x32_bf16(
              af[mi], bq[ni], acc[mi][ni], 0, 0, 0);
    }
  }

  const int col = n0 + wc * 64 + l15;
  const int row0 = m0 + wr * 64 + l4 * 4;
#pragma unroll
  for (int ni = 0; ni < 4; ++ni) {
    const float bv = bias[col + ni * 16];
#pragma unroll
    for (int mi = 0; mi < 4; ++mi)
#pragma unroll
      for (int q = 0; q < 4; ++q)
        Cout[(size_t)(row0 + mi * 16 + q) * N + col + ni * 16] =
            acc[mi][ni][q] + bv;
  }
}

// ---------------- launcher ----------------
extern "C" void kernel_launch(void* const* d_in, const int* in_sizes, int n_in,
                              void* d_out, int out_size, void* d_ws,
                              size_t ws_size, hipStream_t stream) {
  const float* x = (const float*)d_in[0];
  const float* h = (const float*)d_in[1];
  const float* c = (const float*)d_in[2];
  const float* Wi = (const float*)d_in[3];
  const float* bi = (const float*)d_in[4];
  const float* Wf = (const float*)d_in[5];
  const float* bfg = (const float*)d_in[6];
  const float* Wo = (const float*)d_in[7];
  const float* bo = (const float*)d_in[8];
  const float* Wc = (const float*)d_in[9];
  const float* bc = (const float*)d_in[10];
  const float* Wy = (const float*)d_in[11];
  const float* by = (const float*)d_in[12];

  char* ws = (char*)d_ws;
  bf16_t* combined = (bf16_t*)ws;                       // 33.5 MB
  bf16_t* Wt = (bf16_t*)(ws + 33554432);                // 16.8 MB (interleaved)
  bf16_t* Wyt = (bf16_t*)(ws + 33554432 + 16777216);    // 1 MB
  bf16_t* hb = (bf16_t*)(ws + 33554432 + 16777216 + 1048576);  // 16.8 MB

  float* y_out = (float*)d_out;
  float* h_out = y_out + (size_t)B_ * OUT_;
  float* c_out = h_out + (size_t)B_ * H_;

  pack_combined<<<dim3(B_), dim3(256), 0, stream>>>(x, h, combined);
  transpose_all<<<dim3(16, 32, 5), dim3(256), 0, stream>>>(
      Wi, Wf, Wo, Wc, Wy, Wt, Wyt);

  gemm1_8ph<<<dim3((B_ / 256) * (N4 / 256)), dim3(512), 0, stream>>>(
      combined, Wt, c, bi, bfg, bo, bc, h_out, c_out, hb);

  gemm_bt_f32<<<dim3(OUT_ / 128, B_ / 128), dim3(256), 0, stream>>>(
      hb, Wyt, y_out, by, B_, OUT_, H_);
}